// Round 10
// baseline (238.427 us; speedup 1.0000x reference)
//
#include <hip/hip_runtime.h>
#include <math.h>

#define SEQ    4096
#define DMODEL 1024
#define NHEADS 16
#define DK     64

typedef unsigned short u16;
typedef short bh8 __attribute__((ext_vector_type(8)));   // 8 x bf16 (4 VGPRs)
typedef float f4  __attribute__((ext_vector_type(4)));   // 4 x fp32
typedef float f16v __attribute__((ext_vector_type(16))); // 32x32 mfma acc

__device__ __forceinline__ u16 f2b(float f) {            // RNE
    union { float f; unsigned u; } v; v.f = f;
    unsigned u = v.u;
    return (u16)((u + 0x7FFFu + ((u >> 16) & 1u)) >> 16);
}
__device__ __forceinline__ unsigned bits_of(float f) {
    union { float f; unsigned u; } v; v.f = f; return v.u;
}
__device__ __forceinline__ float u2f(unsigned u) {
    union { unsigned u; float f; } v; v.u = u; return v.f;
}
// pack (a,b) -> {a.hi16, b.hi16} (trunc bf16 pair) in ONE v_perm_b32
__device__ __forceinline__ unsigned pk2(float a, float b) {
#if __has_builtin(__builtin_amdgcn_perm)
    return __builtin_amdgcn_perm(bits_of(b), bits_of(a), 0x07060302u);
#else
    return (bits_of(a) >> 16) | (bits_of(b) & 0xFFFF0000u);
#endif
}
__device__ __forceinline__ float fexp2(float x) {
#if __has_builtin(__builtin_amdgcn_exp2f)
    return __builtin_amdgcn_exp2f(x);       // raw v_exp_f32
#else
    return exp2f(x);
#endif
}
__device__ __forceinline__ float ffract(float x) {
#if __has_builtin(__builtin_amdgcn_fractf)
    return __builtin_amdgcn_fractf(x);      // raw v_fract_f32
#else
    return x - floorf(x);
#endif
}

// ---------------------------------------------------------------------------
// Merged fp32 -> bf16 convert for x and all 4 weights (one launch).
// ---------------------------------------------------------------------------
__global__ void cvt_all_kernel(const float* __restrict__ x,
                               const float* __restrict__ wq, const float* __restrict__ wk,
                               const float* __restrict__ wv, const float* __restrict__ wo,
                               u16* __restrict__ xb, u16* __restrict__ wb)
{
    const int NX = SEQ * DMODEL / 8;        // 524288 chunks of 8
    const int NW = DMODEL * DMODEL / 8;     // 131072
    int i = blockIdx.x * blockDim.x + threadIdx.x;
    if (i >= NX + 4 * NW) return;
    const float* src; u16* dst; int j;
    if (i < NX) { src = x; dst = xb; j = i; }
    else {
        int k = i - NX;
        int wsel = k >> 17;                 // NW = 2^17
        j = k & (NW - 1);
        src = (wsel == 0) ? wq : (wsel == 1) ? wk : (wsel == 2) ? wv : wo;
        dst = wb + (size_t)wsel * DMODEL * DMODEL;
    }
    const float4* p = (const float4*)src + (size_t)j * 2;
    float4 a = p[0], b = p[1];
    __align__(16) u16 r[8] = { f2b(a.x), f2b(a.y), f2b(a.z), f2b(a.w),
                               f2b(b.x), f2b(b.y), f2b(b.z), f2b(b.w) };
    *(uint4*)(dst + (size_t)j * 8) = *(const uint4*)r;
}

// ---------------------------------------------------------------------------
// bf16 MFMA GEMM (bt-form), BK=32, 4 waves, prefetch-distance-1 dbuf
// (R7/R8 proven structure; R9's counted-vmcnt distance-2 reverted — it
// regressed, matching the m141 sched-pinning trap).
// MODE 0: 128x64 tile, fp32 out.  MODE 2: 128x128, fused QKV epilogue
// (permuted B staging -> intra-lane RoPE + coalesced Q/K stores; V
// transposed via the staging LDS, coalesced stores). 2D grid (R7 best).
// ---------------------------------------------------------------------------
template<int MODE>
__global__ __launch_bounds__(256) void gemm_bt(
    const u16* __restrict__ A, const u16* __restrict__ B,
    void* __restrict__ out, u16* __restrict__ Qh, u16* __restrict__ Kh,
    u16* __restrict__ Vt, int M, int N, int K)
{
    constexpr int BN  = (MODE == 0) ? 64 : 128;
    constexpr int NJ  = BN / 32;            // j-tiles per wave (2 or 4)
    constexpr int ASZ = 128 * 32;           // 4096 u16
    constexpr int BSZ = BN * 32;

    __shared__ __align__(16) u16 sh[2][ASZ + BSZ];

    const int t    = threadIdx.x;
    const int w    = t >> 6, lane = t & 63;
    const int quad = lane >> 4, l16 = lane & 15;
    const int wm   = w >> 1,  wn  = w & 1;
    const int m0   = blockIdx.y * 128, n0 = blockIdx.x * BN;
    const int lr   = lane >> 2;             // 0..15
    const int lc   = (lane & 3) * 8;        // 0,8,16,24
    const int c0   = 2 * w, c1 = 2 * w + 1;

    f4 acc[4][NJ];
#pragma unroll
    for (int i = 0; i < 4; ++i)
#pragma unroll
        for (int j = 0; j < NJ; ++j) { f4 z = {0.f,0.f,0.f,0.f}; acc[i][j] = z; }

    // per-thread staging source offsets (elements)
    const size_t aofs0 = (size_t)(m0 + c0 * 16 + lr) * K + lc;
    const size_t aofs1 = (size_t)(m0 + c1 * 16 + lr) * K + lc;
    size_t bofs0 = 0, bofs1 = 0;
    if (MODE == 0) {
        bofs0 = (size_t)(n0 + w * 16 + lr) * K + lc;
    } else {
        const int br0 = c0 * 16 + lr, br1 = c1 * 16 + lr;
        const int p0 = (br0 & 64) | ((br0 & 15) << 2) | ((br0 >> 4) & 3);
        const int p1 = (br1 & 64) | ((br1 & 15) << 2) | ((br1 >> 4) & 3);
        bofs0 = (size_t)(n0 + p0) * K + lc;
        bofs1 = (size_t)(n0 + p1) * K + lc;
    }

#define GLD(src_, dst_)                                                        \
    __builtin_amdgcn_global_load_lds(                                          \
        (const __attribute__((address_space(1))) unsigned int*)(src_),         \
        (__attribute__((address_space(3))) unsigned int*)(dst_), 16, 0, 0)

#define STAGE(buf_, k0_) do {                                                  \
    GLD(A + aofs0 + (k0_), &sh[buf_][c0 * 512]);                               \
    GLD(A + aofs1 + (k0_), &sh[buf_][c1 * 512]);                               \
    if (MODE == 0) {                                                           \
        GLD(B + bofs0 + (k0_), &sh[buf_][ASZ + w * 512]);                      \
    } else {                                                                   \
        GLD(B + bofs0 + (k0_), &sh[buf_][ASZ + c0 * 512]);                     \
        GLD(B + bofs1 + (k0_), &sh[buf_][ASZ + c1 * 512]);                     \
    }                                                                          \
} while (0)

    STAGE(0, 0);
    __syncthreads();                        // tile 0 resident

    int b = 0;
    for (int k0 = 0; k0 < K; k0 += 32) {
        if (k0 + 32 < K) STAGE(b ^ 1, k0 + 32);   // prefetch next tile

        const u16* As_ = &sh[b][0];
        const u16* Bs_ = &sh[b][ASZ];
        bh8 af[4], bf_[NJ];
#pragma unroll
        for (int i = 0; i < 4; ++i)
            af[i] = *(const bh8*)&As_[(wm * 64 + i * 16 + l16) * 32 + quad * 8];
#pragma unroll
        for (int j = 0; j < NJ; ++j)
            bf_[j] = *(const bh8*)&Bs_[(wn * (BN / 2) + j * 16 + l16) * 32 + quad * 8];
#pragma unroll
        for (int i = 0; i < 4; ++i)
#pragma unroll
            for (int j = 0; j < NJ; ++j)
                acc[i][j] = __builtin_amdgcn_mfma_f32_16x16x32_bf16(af[i], bf_[j], acc[i][j], 0, 0, 0);
        __syncthreads();                    // drains prefetch; frees buf b
        b ^= 1;
    }

    if (MODE == 0) {
#pragma unroll
        for (int i = 0; i < 4; ++i) {
            const int row = m0 + wm * 64 + i * 16 + quad * 4;
#pragma unroll
            for (int j = 0; j < NJ; ++j) {
                const int col = n0 + wn * (BN / 2) + j * 16 + l16;
#pragma unroll
                for (int r = 0; r < 4; ++r)
                    ((float*)out)[(size_t)(row + r) * N + col] = acc[i][j][r];
            }
        }
    } else {
        const int sect = n0 >> 10;                    // 0=Q,1=K,2=V
        if (sect < 2) {
            // ---- Q/K: intra-lane RoPE, coalesced 8B stores ----
            const int hh = ((n0 & 1023) + wn * 64) >> 6;
            u16* dst = (sect == 0) ? Qh : Kh;
            const float qscl = (sect == 0) ? 0.18033688011112042f : 1.0f; // 0.125*log2(e)
            const int dbase = l16 * 4;                // d = dbase + j
            const float invfA = exp2f((float)(dbase)     * (-13.287712379549449f / 64.0f))
                                * 0.15915494309189535f;
            const float invfB = exp2f((float)(dbase + 2) * (-13.287712379549449f / 64.0f))
                                * 0.15915494309189535f;
#pragma unroll
            for (int i = 0; i < 4; ++i) {
                const int srow0 = m0 + wm * 64 + i * 16 + quad * 4;
#pragma unroll
                for (int r = 0; r < 4; ++r) {
                    const int srow = srow0 + r;
                    const float revA = ffract((float)srow * invfA);
                    const float revB = ffract((float)srow * invfB);
                    const float snA = __builtin_amdgcn_sinf(revA);
                    const float csA = __builtin_amdgcn_cosf(revA);
                    const float snB = __builtin_amdgcn_sinf(revB);
                    const float csB = __builtin_amdgcn_cosf(revB);
                    const float e0 = acc[i][0][r], o0 = acc[i][1][r];
                    const float e1 = acc[i][2][r], o1 = acc[i][3][r];
                    const float v0 = (csA * e0 - snA * o0) * qscl;
                    const float v1 = (snA * e0 + csA * o0) * qscl;
                    const float v2 = (csB * e1 - snB * o1) * qscl;
                    const float v3 = (snB * e1 + csB * o1) * qscl;
                    uint2 st;
                    st.x = (unsigned)f2b(v0) | ((unsigned)f2b(v1) << 16);
                    st.y = (unsigned)f2b(v2) | ((unsigned)f2b(v3) << 16);
                    *(uint2*)&dst[((size_t)hh * SEQ + srow) * DK + dbase] = st;
                }
            }
        } else {
            // ---- V: transpose via the 32KB staging LDS, coalesced stores ----
            u16* scr = &sh[0][0];                     // 16384 u16 = 32KB
            const int cfb = wn * 64 + l16 * 4;        // + j
            const int xv  = (l16 & 7) << 2;           // ((cfb+j)>>2)&7 == l16&7
            __syncthreads();                          // staging reads all done
#pragma unroll
            for (int i = 0; i < 4; ++i) {
                const int s0 = wm * 64 + i * 16 + quad * 4;
                const int s8 = s0 >> 2;
#pragma unroll
                for (int j = 0; j < NJ; ++j) {
                    __align__(8) u16 pk[4];
#pragma unroll
                    for (int r = 0; r < 4; ++r) pk[r] = f2b(acc[i][j][r]);
                    *(unsigned long long*)&scr[(cfb + j) * 128 + (s8 ^ xv) * 4] =
                        *(const unsigned long long*)pk;
                }
            }
            __syncthreads();
            const int hh0 = (n0 & 1023) >> 6;
            const int sl  = t & 15;                   // s-chunk (16B each)
#pragma unroll
            for (int jj = 0; jj < 8; ++jj) {
                const int cfull = jj * 16 + (t >> 4);
                const int hd    = hh0 + (cfull >> 6);
                const int dd    = cfull & 63;
                const int rxv   = ((cfull >> 2) & 7) << 2;
                bh8 vv = *(const bh8*)&scr[cfull * 128 + ((sl * 2) ^ rxv) * 4];
                *(bh8*)&Vt[((size_t)hd * DK + dd) * SEQ + m0 + sl * 8] = vv;
            }
        }
    }
#undef STAGE
#undef GLD
}

// ---------------------------------------------------------------------------
// MFMA flash attention, 32x32x16. R10: occupancy 2 -> 3 blocks/CU.
//  * LDS 64 -> 48 KB: K double-buffered (2x16KB), V SINGLE-buffered (16KB).
//  * Per step, 2 barriers with counted handoffs (FIFO vmcnt):
//      P3[vmcnt(0)+bar]: K(k) resident (issued a full step ago -> cheap
//                        drain), Vs free (all PV(k-1) reads done)
//      STAGE_V(k); STAGE_K(k+1)            // V latency covered by QK+exp
//      QK(k), mask, exp
//      P2[vmcnt(2)+bar]: drains exactly the older V pair; K(k+1) stays
//                        in flight across the barrier
//      PV(k)
//  * Grid 1024 (one q-tile/block, longest-first = LPT packing; same
//    head-per-XCD mapping). launch_bounds (512,6) for 3 blocks/CU.
//  * Epilogue merge partials packed to RNE-bf16 (scratch fits 32KB K region;
//    error budget ~+0.006 on absmax 0.0195 vs threshold 0.0597).
// ---------------------------------------------------------------------------
__global__ __launch_bounds__(512, 6) void attn_mfma_kernel(
    const u16* __restrict__ Qh, const u16* __restrict__ Kh,
    const u16* __restrict__ Vt, u16* __restrict__ ctx)
{
    __shared__ __align__(16) u16 Ks[2][8192];   // [buf][128 keys][64 d] swizzled
    __shared__ __align__(16) u16 Vs[8192];      // [64 d][128 keys'] permuted+swz

    const int id   = blockIdx.x;                 // 0..1023
    const int head = (id & 7) + 8 * ((id >> 3) & 1);
    const int qt   = 63 - (id >> 4);             // longest blocks first (LPT)

    const int t    = threadIdx.x;                // 0..511
    const int w    = t >> 6, lane = t & 63;
    const int qb   = w & 1, kb = w >> 1;         // q-subtile, key-block
    const int l31  = lane & 31, hl = lane >> 5;
    const int r7   = l31 & 7;

    const u16* Kbase = Kh + (size_t)head * SEQ * DK;
    const u16* Vbase = Vt + (size_t)head * DK * SEQ;

    int kread[4];
#pragma unroll
    for (int c = 0; c < 4; ++c)
        kread[c] = (kb * 32 + l31) * 64 + (((c * 2 + hl) ^ r7) * 8);
    int vread[2][2];
#pragma unroll
    for (int db = 0; db < 2; ++db)
#pragma unroll
        for (int kc = 0; kc < 2; ++kc)
            vread[db][kc] = (db * 32 + l31) * 128
                          + (((kb * 4 + kc * 2 + hl) ^ r7) * 8);

    int koff[2], voff[2];
#pragma unroll
    for (int i = 0; i < 2; ++i) {
        const int krow = i * 64 + (t >> 3);       // 0..127
        koff[i] = krow * DK + (((t & 7) ^ (krow & 7)) * 8);
        const int vdr  = i * 32 + (t >> 4);       // 0..63
        voff[i] = vdr * SEQ + (((t & 15) ^ (vdr & 7)) * 8);
    }
    const int dstKV = w * 512;                    // u16 units, + i*4096

    const f16v z16 = {0,0,0,0,0,0,0,0,0,0,0,0,0,0,0,0};

#define STAGE_K(buf_, kt_) do {                                                \
    _Pragma("unroll")                                                          \
    for (int i_ = 0; i_ < 2; ++i_)                                             \
        __builtin_amdgcn_global_load_lds(                                      \
            (const __attribute__((address_space(1))) unsigned int*)            \
                (Kbase + (size_t)(kt_) * 128 * DK + koff[i_]),                 \
            (__attribute__((address_space(3))) unsigned int*)                  \
                &Ks[buf_][i_ * 4096 + dstKV], 16, 0, 0);                       \
} while (0)

#define STAGE_V(kt_) do {                                                      \
    _Pragma("unroll")                                                          \
    for (int i_ = 0; i_ < 2; ++i_)                                             \
        __builtin_amdgcn_global_load_lds(                                      \
            (const __attribute__((address_space(1))) unsigned int*)            \
                (Vbase + (kt_) * 128 + voff[i_]),                              \
            (__attribute__((address_space(3))) unsigned int*)                  \
                &Vs[i_ * 4096 + dstKV], 16, 0, 0);                             \
} while (0)

    const int q0 = qt * 64;
    const int nt = qt / 2 + 1;
    const int qg = q0 + qb * 32 + l31;            // this lane's q row

    // Q fragments (B-operand: n=l31=q, k=hl*8+j within d-chunk)
    bh8 qa[4];
    {
        const u16* qrow = Qh + ((size_t)head * SEQ + qg) * DK;
#pragma unroll
        for (int c = 0; c < 4; ++c)
            qa[c] = *(const bh8*)(qrow + c * 16 + hl * 8);
    }

    f16v o0 = z16;
    f16v o1 = z16;
    float lsum = 0.f;

    // prologue: K(0) in flight
    STAGE_K(0, 0);

    int b = 0;
    for (int kt = 0; kt < nt; ++kt) {
        // P3: K(kt) resident across waves; Vs free (prev PV reads done)
        __builtin_amdgcn_sched_barrier(0);
        asm volatile("s_waitcnt vmcnt(0)" ::: "memory");
        __builtin_amdgcn_s_barrier();
        __builtin_amdgcn_sched_barrier(0);

        STAGE_V(kt);                              // covered by QK+exp below
        if (kt + 1 < nt) STAGE_K(b ^ 1, kt + 1);  // covered by a full step

        const int  kbase = kt * 128;
        const bool diag  = (kt == nt - 1);
        const bool skip  = diag && (kbase + kb * 32 > q0 + qb * 32 + 31);

        float p[16];
        if (!skip) {
            __builtin_amdgcn_s_setprio(1);
            bh8 kf0 = *(const bh8*)&Ks[b][kread[0]];
            f16v s = __builtin_amdgcn_mfma_f32_32x32x16_bf16(kf0, qa[0], z16, 0, 0, 0);
#pragma unroll
            for (int c = 1; c < 4; ++c) {
                bh8 kf = *(const bh8*)&Ks[b][kread[c]];
                s = __builtin_amdgcn_mfma_f32_32x32x16_bf16(kf, qa[c], s, 0, 0, 0);
            }
            __builtin_amdgcn_s_setprio(0);
            if (diag) {
#pragma unroll
                for (int r = 0; r < 16; ++r) {
                    const int keyg = kbase + kb * 32 + (r & 3) + 8 * (r >> 2) + 4 * hl;
                    if (keyg > qg) s[r] = -1.0e30f;
                }
            }
#pragma unroll
            for (int r = 0; r < 16; ++r) { p[r] = fexp2(s[r]); lsum += p[r]; }
        }

        // P2: V(kt) resident (FIFO vmcnt: drains the older V pair only;
        // K(kt+1) stays in flight across the barrier)
        __builtin_amdgcn_sched_barrier(0);
        if (kt + 1 < nt) asm volatile("s_waitcnt vmcnt(2)" ::: "memory");
        else             asm volatile("s_waitcnt vmcnt(0)" ::: "memory");
        __builtin_amdgcn_s_barrier();
        __builtin_amdgcn_sched_barrier(0);

        if (!skip) {
#pragma unroll
            for (int kc = 0; kc < 2; ++kc) {
                unsigned A0 = pk2(p[kc*8+0], p[kc*8+1]);
                unsigned A1 = pk2(p[kc*8+2], p[kc*8+3]);
                unsigned A2 = pk2(p[kc*8+4], p[kc*8+5]);
                unsigned A3 = pk2(p[kc*8+6], p[kc*8+7]);
                asm volatile("v_permlane32_swap_b32 %0, %1" : "+v"(A0), "+v"(A2));
                asm volatile("v_permlane32_swap_b32 %0, %1" : "+v"(A1), "+v"(A3));
                union { unsigned u[4]; bh8 v; } pb;
                pb.u[0] = A0; pb.u[1] = A1; pb.u[2] = A2; pb.u[3] = A3;
                bh8 va0 = *(const bh8*)&Vs[vread[0][kc]];
                bh8 va1 = *(const bh8*)&Vs[vread[1][kc]];
                __builtin_amdgcn_s_setprio(1);
                o0 = __builtin_amdgcn_mfma_f32_32x32x16_bf16(va0, pb.v, o0, 0, 0, 0);
                o1 = __builtin_amdgcn_mfma_f32_32x32x16_bf16(va1, pb.v, o1, 0, 0, 0);
                __builtin_amdgcn_s_setprio(0);
            }
        }
        b ^= 1;
    }

    // ---- epilogue: reduce l across lane-halves; 4-way kb merge ----
    lsum += __shfl_xor(lsum, 32);
    __syncthreads();                  // all K/V LDS reads done -> scratch OK
    // records: 6 waves x 64 lanes x 20 u32 (16 bf16x2-packed O + 1 f32 l).
    // fits in Ks (30.7KB < 32KB). 2-word ops at stride 20: worst 2-way (free).
    unsigned* scru = (unsigned*)&Ks[0][0];
    union { f16v v; f4 q[4]; } uo0, uo1;
    uo0.v = o0; uo1.v = o1;
    if (kb != 0) {
        unsigned* rec = scru + (((kb - 1) * 2 + qb) * 64 + lane) * 20;
#pragma unroll
        for (int j = 0; j < 4; ++j) {
            rec[j*2]     = (unsigned)f2b(uo0.q[j][0]) | ((unsigned)f2b(uo0.q[j][1]) << 16);
            rec[j*2 + 1] = (unsigned)f2b(uo0.q[j][2]) | ((unsigned)f2b(uo0.q[j][3]) << 16);
            rec[8 + j*2]     = (unsigned)f2b(uo1.q[j][0]) | ((unsigned)f2b(uo1.q[j][1]) << 16);
            rec[8 + j*2 + 1] = (unsigned)f2b(uo1.q[j][2]) | ((unsigned)f2b(uo1.q[j][3]) << 16);
        }
        ((float*)rec)[16] = lsum;
    }
    __syncthreads();
    if (kb == 0) {
#pragma unroll
        for (int jr = 0; jr < 3; ++jr) {
            const unsigned* rec = scru + ((jr * 2 + qb) * 64 + lane) * 20;
#pragma unroll
            for (int j = 0; j < 4; ++j) {
                const unsigned a0 = rec[j*2],     a1 = rec[j*2 + 1];
                const unsigned c0 = rec[8 + j*2], c1 = rec[8 + j*2 + 1];
                uo0.q[j][0] += u2f(a0 << 16);  uo0.q[j][1] += u2f(a0 & 0xFFFF0000u);
                uo0.q[j][2] += u2f(a1 << 16);  uo0.q[j][3] += u2f(a1 & 0xFFFF0000u);
                uo1.q[j][0] += u2f(c0 << 16);  uo1.q[j][1] += u2f(c0 & 0xFFFF0000u);
                uo1.q[j][2] += u2f(c1 << 16);  uo1.q[j][3] += u2f(c1 & 0xFFFF0000u);
            }
            lsum += ((const float*)rec)[16];
        }
        const float linv = 1.f / lsum;
        const size_t rowbase = (size_t)qg * DMODEL + head * DK;
#pragma unroll
        for (int a = 0; a < 4; ++a) {
            unsigned lo = (unsigned)f2b(uo0.q[a][0] * linv) | ((unsigned)f2b(uo0.q[a][1] * linv) << 16);
            unsigned hi = (unsigned)f2b(uo0.q[a][2] * linv) | ((unsigned)f2b(uo0.q[a][3] * linv) << 16);
            uint2 pkd; pkd.x = lo; pkd.y = hi;
            *(uint2*)&ctx[rowbase + a * 8 + 4 * hl] = pkd;
            lo = (unsigned)f2b(uo1.q[a][0] * linv) | ((unsigned)f2b(uo1.q[a][1] * linv) << 16);
            hi = (unsigned)f2b(uo1.q[a][2] * linv) | ((unsigned)f2b(uo1.q[a][3] * linv) << 16);
            pkd.x = lo; pkd.y = hi;
            *(uint2*)&ctx[rowbase + 32 + a * 8 + 4 * hl] = pkd;
        }
    }
#undef STAGE_K
#undef STAGE_V
}

// ---------------------------------------------------------------------------
extern "C" void kernel_launch(void* const* d_in, const int* in_sizes, int n_in,
                              void* d_out, int out_size, void* d_ws, size_t ws_size,
                              hipStream_t stream)
{
    const float* x  = (const float*)d_in[0];
    const float* wq = (const float*)d_in[1];
    const float* wk = (const float*)d_in[2];
    const float* wv = (const float*)d_in[3];
    const float* wo = (const float*)d_in[4];
    float* out = (float*)d_out;

    char* ws = (char*)d_ws;
    const size_t MB = 1u << 20;
    u16* xb   = (u16*)(ws);              // 8 MB  [4096][1024] bf16
    u16* wqkv = (u16*)(ws + 8  * MB);    // 6 MB  [3072][1024] bf16 (wq|wk|wv)
    u16* wob  = (u16*)(ws + 14 * MB);    // 2 MB  (contiguous after wqkv)
    u16* Qh   = (u16*)(ws + 16 * MB);    // 8 MB  [h][s][64]  (pre-scaled)
    u16* Kh   = (u16*)(ws + 24 * MB);    // 8 MB
    u16* Vtb  = (u16*)(ws + 32 * MB);    // 8 MB  [h][64][s]
    u16* ctxb = (u16*)(ws + 40 * MB);    // 8 MB  [s][1024]

    const int NCVT = SEQ * DMODEL / 8 + 4 * (DMODEL * DMODEL / 8);   // 1048576
    cvt_all_kernel<<<NCVT / 256, 256, 0, stream>>>(x, wq, wk, wv, wo, xb, wqkv);

    dim3 gqkv(3 * DMODEL / 128, SEQ / 128);   // (24, 32) = 768 blocks
    gemm_bt<2><<<gqkv, 256, 0, stream>>>(xb, wqkv, nullptr, Qh, Kh, Vtb,
                                         SEQ, 3 * DMODEL, DMODEL);

    attn_mfma_kernel<<<dim3(1024), 512, 0, stream>>>(Qh, Kh, Vtb, ctxb);

    dim3 go(DMODEL / 64, SEQ / 128);          // (16, 32) = 512 blocks
    gemm_bt<0><<<go, 256, 0, stream>>>(ctxb, wob, out, nullptr, nullptr, nullptr,
                                       SEQ, DMODEL, DMODEL);
}

// Round 11
// 185.917 us; speedup vs baseline: 1.2824x; 1.2824x over previous
//
#include <hip/hip_runtime.h>
#include <math.h>

#define SEQ    4096
#define DMODEL 1024
#define NHEADS 16
#define DK     64

typedef unsigned short u16;
typedef short bh8 __attribute__((ext_vector_type(8)));   // 8 x bf16 (4 VGPRs)
typedef float f4  __attribute__((ext_vector_type(4)));   // 4 x fp32
typedef float f16v __attribute__((ext_vector_type(16))); // 32x32 mfma acc

__device__ __forceinline__ u16 f2b(float f) {            // RNE
    union { float f; unsigned u; } v; v.f = f;
    unsigned u = v.u;
    return (u16)((u + 0x7FFFu + ((u >> 16) & 1u)) >> 16);
}
__device__ __forceinline__ unsigned bits_of(float f) {
    union { float f; unsigned u; } v; v.f = f; return v.u;
}
// pack (a,b) -> {a.hi16, b.hi16} (trunc bf16 pair) in ONE v_perm_b32
__device__ __forceinline__ unsigned pk2(float a, float b) {
#if __has_builtin(__builtin_amdgcn_perm)
    return __builtin_amdgcn_perm(bits_of(b), bits_of(a), 0x07060302u);
#else
    return (bits_of(a) >> 16) | (bits_of(b) & 0xFFFF0000u);
#endif
}
__device__ __forceinline__ float fexp2(float x) {
#if __has_builtin(__builtin_amdgcn_exp2f)
    return __builtin_amdgcn_exp2f(x);       // raw v_exp_f32
#else
    return exp2f(x);
#endif
}
__device__ __forceinline__ float ffract(float x) {
#if __has_builtin(__builtin_amdgcn_fractf)
    return __builtin_amdgcn_fractf(x);      // raw v_fract_f32
#else
    return x - floorf(x);
#endif
}

// ---------------------------------------------------------------------------
// Merged fp32 -> bf16 convert for x and all 4 weights (one launch).
// ---------------------------------------------------------------------------
__global__ void cvt_all_kernel(const float* __restrict__ x,
                               const float* __restrict__ wq, const float* __restrict__ wk,
                               const float* __restrict__ wv, const float* __restrict__ wo,
                               u16* __restrict__ xb, u16* __restrict__ wb)
{
    const int NX = SEQ * DMODEL / 8;        // 524288 chunks of 8
    const int NW = DMODEL * DMODEL / 8;     // 131072
    int i = blockIdx.x * blockDim.x + threadIdx.x;
    if (i >= NX + 4 * NW) return;
    const float* src; u16* dst; int j;
    if (i < NX) { src = x; dst = xb; j = i; }
    else {
        int k = i - NX;
        int wsel = k >> 17;                 // NW = 2^17
        j = k & (NW - 1);
        src = (wsel == 0) ? wq : (wsel == 1) ? wk : (wsel == 2) ? wv : wo;
        dst = wb + (size_t)wsel * DMODEL * DMODEL;
    }
    const float4* p = (const float4*)src + (size_t)j * 2;
    float4 a = p[0], b = p[1];
    __align__(16) u16 r[8] = { f2b(a.x), f2b(a.y), f2b(a.z), f2b(a.w),
                               f2b(b.x), f2b(b.y), f2b(b.z), f2b(b.w) };
    *(uint4*)(dst + (size_t)j * 8) = *(const uint4*)r;
}

// ---------------------------------------------------------------------------
// bf16 MFMA GEMM (bt-form), BK=32, 4 waves, prefetch-distance-1 dbuf —
// the best-measured structure (R7: non-attn 122.6us). R9's counted-vmcnt
// distance-2 and R10's variants are reverted (both regressed; m141-class
// sched-pinning trap). 2D grid.
// MODE 0: 128x64 tile, fp32 out.  MODE 2: 128x128, fused QKV epilogue
// (permuted B staging -> intra-lane RoPE + coalesced Q/K stores; V
// transposed via the staging LDS, coalesced stores).
// ---------------------------------------------------------------------------
template<int MODE>
__global__ __launch_bounds__(256) void gemm_bt(
    const u16* __restrict__ A, const u16* __restrict__ B,
    void* __restrict__ out, u16* __restrict__ Qh, u16* __restrict__ Kh,
    u16* __restrict__ Vt, int M, int N, int K)
{
    constexpr int BN  = (MODE == 0) ? 64 : 128;
    constexpr int NJ  = BN / 32;            // j-tiles per wave (2 or 4)
    constexpr int ASZ = 128 * 32;           // 4096 u16
    constexpr int BSZ = BN * 32;

    __shared__ __align__(16) u16 sh[2][ASZ + BSZ];

    const int t    = threadIdx.x;
    const int w    = t >> 6, lane = t & 63;
    const int quad = lane >> 4, l16 = lane & 15;
    const int wm   = w >> 1,  wn  = w & 1;
    const int m0   = blockIdx.y * 128, n0 = blockIdx.x * BN;
    const int lr   = lane >> 2;             // 0..15
    const int lc   = (lane & 3) * 8;        // 0,8,16,24
    const int c0   = 2 * w, c1 = 2 * w + 1;

    f4 acc[4][NJ];
#pragma unroll
    for (int i = 0; i < 4; ++i)
#pragma unroll
        for (int j = 0; j < NJ; ++j) { f4 z = {0.f,0.f,0.f,0.f}; acc[i][j] = z; }

    // per-thread staging source offsets (elements)
    const size_t aofs0 = (size_t)(m0 + c0 * 16 + lr) * K + lc;
    const size_t aofs1 = (size_t)(m0 + c1 * 16 + lr) * K + lc;
    size_t bofs0 = 0, bofs1 = 0;
    if (MODE == 0) {
        bofs0 = (size_t)(n0 + w * 16 + lr) * K + lc;
    } else {
        const int br0 = c0 * 16 + lr, br1 = c1 * 16 + lr;
        const int p0 = (br0 & 64) | ((br0 & 15) << 2) | ((br0 >> 4) & 3);
        const int p1 = (br1 & 64) | ((br1 & 15) << 2) | ((br1 >> 4) & 3);
        bofs0 = (size_t)(n0 + p0) * K + lc;
        bofs1 = (size_t)(n0 + p1) * K + lc;
    }

#define GLD(src_, dst_)                                                        \
    __builtin_amdgcn_global_load_lds(                                          \
        (const __attribute__((address_space(1))) unsigned int*)(src_),         \
        (__attribute__((address_space(3))) unsigned int*)(dst_), 16, 0, 0)

#define STAGE(buf_, k0_) do {                                                  \
    GLD(A + aofs0 + (k0_), &sh[buf_][c0 * 512]);                               \
    GLD(A + aofs1 + (k0_), &sh[buf_][c1 * 512]);                               \
    if (MODE == 0) {                                                           \
        GLD(B + bofs0 + (k0_), &sh[buf_][ASZ + w * 512]);                      \
    } else {                                                                   \
        GLD(B + bofs0 + (k0_), &sh[buf_][ASZ + c0 * 512]);                     \
        GLD(B + bofs1 + (k0_), &sh[buf_][ASZ + c1 * 512]);                     \
    }                                                                          \
} while (0)

    STAGE(0, 0);
    __syncthreads();                        // tile 0 resident

    int b = 0;
    for (int k0 = 0; k0 < K; k0 += 32) {
        if (k0 + 32 < K) STAGE(b ^ 1, k0 + 32);   // prefetch next tile

        const u16* As_ = &sh[b][0];
        const u16* Bs_ = &sh[b][ASZ];
        bh8 af[4], bf_[NJ];
#pragma unroll
        for (int i = 0; i < 4; ++i)
            af[i] = *(const bh8*)&As_[(wm * 64 + i * 16 + l16) * 32 + quad * 8];
#pragma unroll
        for (int j = 0; j < NJ; ++j)
            bf_[j] = *(const bh8*)&Bs_[(wn * (BN / 2) + j * 16 + l16) * 32 + quad * 8];
#pragma unroll
        for (int i = 0; i < 4; ++i)
#pragma unroll
            for (int j = 0; j < NJ; ++j)
                acc[i][j] = __builtin_amdgcn_mfma_f32_16x16x32_bf16(af[i], bf_[j], acc[i][j], 0, 0, 0);
        __syncthreads();                    // drains prefetch; frees buf b
        b ^= 1;
    }

    if (MODE == 0) {
#pragma unroll
        for (int i = 0; i < 4; ++i) {
            const int row = m0 + wm * 64 + i * 16 + quad * 4;
#pragma unroll
            for (int j = 0; j < NJ; ++j) {
                const int col = n0 + wn * (BN / 2) + j * 16 + l16;
#pragma unroll
                for (int r = 0; r < 4; ++r)
                    ((float*)out)[(size_t)(row + r) * N + col] = acc[i][j][r];
            }
        }
    } else {
        const int sect = n0 >> 10;                    // 0=Q,1=K,2=V
        if (sect < 2) {
            // ---- Q/K: intra-lane RoPE, coalesced 8B stores ----
            const int hh = ((n0 & 1023) + wn * 64) >> 6;
            u16* dst = (sect == 0) ? Qh : Kh;
            const float qscl = (sect == 0) ? 0.18033688011112042f : 1.0f; // 0.125*log2(e)
            const int dbase = l16 * 4;                // d = dbase + j
            const float invfA = exp2f((float)(dbase)     * (-13.287712379549449f / 64.0f))
                                * 0.15915494309189535f;
            const float invfB = exp2f((float)(dbase + 2) * (-13.287712379549449f / 64.0f))
                                * 0.15915494309189535f;
#pragma unroll
            for (int i = 0; i < 4; ++i) {
                const int srow0 = m0 + wm * 64 + i * 16 + quad * 4;
#pragma unroll
                for (int r = 0; r < 4; ++r) {
                    const int srow = srow0 + r;
                    const float revA = ffract((float)srow * invfA);
                    const float revB = ffract((float)srow * invfB);
                    const float snA = __builtin_amdgcn_sinf(revA);
                    const float csA = __builtin_amdgcn_cosf(revA);
                    const float snB = __builtin_amdgcn_sinf(revB);
                    const float csB = __builtin_amdgcn_cosf(revB);
                    const float e0 = acc[i][0][r], o0 = acc[i][1][r];
                    const float e1 = acc[i][2][r], o1 = acc[i][3][r];
                    const float v0 = (csA * e0 - snA * o0) * qscl;
                    const float v1 = (snA * e0 + csA * o0) * qscl;
                    const float v2 = (csB * e1 - snB * o1) * qscl;
                    const float v3 = (snB * e1 + csB * o1) * qscl;
                    uint2 st;
                    st.x = (unsigned)f2b(v0) | ((unsigned)f2b(v1) << 16);
                    st.y = (unsigned)f2b(v2) | ((unsigned)f2b(v3) << 16);
                    *(uint2*)&dst[((size_t)hh * SEQ + srow) * DK + dbase] = st;
                }
            }
        } else {
            // ---- V: transpose via the 32KB staging LDS, coalesced stores ----
            u16* scr = &sh[0][0];                     // 16384 u16 = 32KB
            const int cfb = wn * 64 + l16 * 4;        // + j
            const int xv  = (l16 & 7) << 2;           // ((cfb+j)>>2)&7 == l16&7
            __syncthreads();                          // staging reads all done
#pragma unroll
            for (int i = 0; i < 4; ++i) {
                const int s0 = wm * 64 + i * 16 + quad * 4;
                const int s8 = s0 >> 2;
#pragma unroll
                for (int j = 0; j < NJ; ++j) {
                    __align__(8) u16 pk[4];
#pragma unroll
                    for (int r = 0; r < 4; ++r) pk[r] = f2b(acc[i][j][r]);
                    *(unsigned long long*)&scr[(cfb + j) * 128 + (s8 ^ xv) * 4] =
                        *(const unsigned long long*)pk;
                }
            }
            __syncthreads();
            const int hh0 = (n0 & 1023) >> 6;
            const int sl  = t & 15;                   // s-chunk (16B each)
#pragma unroll
            for (int jj = 0; jj < 8; ++jj) {
                const int cfull = jj * 16 + (t >> 4);
                const int hd    = hh0 + (cfull >> 6);
                const int dd    = cfull & 63;
                const int rxv   = ((cfull >> 2) & 7) << 2;
                bh8 vv = *(const bh8*)&scr[cfull * 128 + ((sl * 2) ^ rxv) * 4];
                *(bh8*)&Vt[((size_t)hd * DK + dd) * SEQ + m0 + sl * 8] = vv;
            }
        }
    }
#undef STAGE
#undef GLD
}

// ---------------------------------------------------------------------------
// MFMA flash attention, 32x32x16 — the best-measured version (R9: 54.8us;
// R10's single-buffered-V counted-handoff variant reverted: it doubled
// attn time and blew FETCH 17->80MB). KV-tile 128; 8 waves = (kb 0..3) x
// (qb 0..1); K/V staged by global_load_lds with source-side bank swizzle;
// single barrier per steady-state step (prefetch distance 1); P crosses
// lane-halves via permlane32_swap; stride-36 merge scratch; head-per-XCD
// grid swizzle; serpentine two-part q-tile pairing (zero imbalance).
// ---------------------------------------------------------------------------
__global__ __launch_bounds__(512, 4) void attn_mfma_kernel(
    const u16* __restrict__ Qh, const u16* __restrict__ Kh,
    const u16* __restrict__ Vt, u16* __restrict__ ctx)
{
    // [buf][ K: 128x64 (8192 u16) | V: 64x128 (8192 u16) ]
    __shared__ __align__(16) u16 smem[2][16384];

    const int id   = blockIdx.x;
    const int head = (id & 7) + 8 * ((id >> 3) & 1);
    const int bx   = id >> 4;                     // 0..31

    const int t    = threadIdx.x;                 // 0..511
    const int w    = t >> 6, lane = t & 63;
    const int qb   = w & 1, kb = w >> 1;          // q-subtile, key-block
    const int l31  = lane & 31, hl = lane >> 5;
    const int r7   = l31 & 7;

    const u16* Kbase = Kh + (size_t)head * SEQ * DK;
    const u16* Vbase = Vt + (size_t)head * DK * SEQ;

    int kread[4];
#pragma unroll
    for (int c = 0; c < 4; ++c)
        kread[c] = (kb * 32 + l31) * 64 + (((c * 2 + hl) ^ r7) * 8);
    int vread[2][2];
#pragma unroll
    for (int db = 0; db < 2; ++db)
#pragma unroll
        for (int kc = 0; kc < 2; ++kc)
            vread[db][kc] = (db * 32 + l31) * 128
                          + (((kb * 4 + kc * 2 + hl) ^ r7) * 8);

    int koff[2], voff[2];
#pragma unroll
    for (int i = 0; i < 2; ++i) {
        const int krow = i * 64 + (t >> 3);       // 0..127
        koff[i] = krow * DK + (((t & 7) ^ (krow & 7)) * 8);
        const int vdr  = i * 32 + (t >> 4);       // 0..63
        voff[i] = vdr * SEQ + (((t & 15) ^ (vdr & 7)) * 8);
    }
    const int dstK = w * 512;
    const int dstV = 8192 + w * 512;

    const f16v z16 = {0,0,0,0,0,0,0,0,0,0,0,0,0,0,0,0};

#define STAGE(buf_, kbase_) do {                                               \
    _Pragma("unroll")                                                          \
    for (int i_ = 0; i_ < 2; ++i_) {                                           \
        __builtin_amdgcn_global_load_lds(                                      \
            (const __attribute__((address_space(1))) unsigned int*)            \
                (Kbase + (size_t)(kbase_) * DK + koff[i_]),                    \
            (__attribute__((address_space(3))) unsigned int*)                  \
                &smem[buf_][i_ * 4096 + dstK], 16, 0, 0);                      \
        __builtin_amdgcn_global_load_lds(                                      \
            (const __attribute__((address_space(1))) unsigned int*)            \
                (Vbase + (kbase_) + voff[i_]),                                 \
            (__attribute__((address_space(3))) unsigned int*)                  \
                &smem[buf_][i_ * 4096 + dstV], 16, 0, 0);                      \
    }                                                                          \
} while (0)

    for (int part = 0; part < 2; ++part) {
        const int qt = part ? (63 - bx) : bx;
        const int q0 = qt * 64;
        const int nt = qt / 2 + 1;
        const int qg = q0 + qb * 32 + l31;        // this lane's q row

        bh8 qa[4];
        {
            const u16* qrow = Qh + ((size_t)head * SEQ + qg) * DK;
#pragma unroll
            for (int c = 0; c < 4; ++c)
                qa[c] = *(const bh8*)(qrow + c * 16 + hl * 8);
        }

        f16v o0 = z16;
        f16v o1 = z16;
        float lsum = 0.f;

        __syncthreads();
        STAGE(0, 0);
        __syncthreads();

        int b = 0;
        for (int kt = 0; kt < nt; ++kt) {
            const bool have_next = (kt + 1 < nt);
            if (have_next) STAGE(b ^ 1, (kt + 1) * 128);

            const int  kbase = kt * 128;
            const bool diag  = (kt == nt - 1);
            const bool skip  = diag && (kbase + kb * 32 > q0 + qb * 32 + 31);

            if (!skip) {
                __builtin_amdgcn_s_setprio(1);
                bh8 kf0 = *(const bh8*)&smem[b][kread[0]];
                f16v s = __builtin_amdgcn_mfma_f32_32x32x16_bf16(kf0, qa[0], z16, 0, 0, 0);
#pragma unroll
                for (int c = 1; c < 4; ++c) {
                    bh8 kf = *(const bh8*)&smem[b][kread[c]];
                    s = __builtin_amdgcn_mfma_f32_32x32x16_bf16(kf, qa[c], s, 0, 0, 0);
                }
                __builtin_amdgcn_s_setprio(0);
                if (diag) {
#pragma unroll
                    for (int r = 0; r < 16; ++r) {
                        const int keyg = kbase + kb * 32 + (r & 3) + 8 * (r >> 2) + 4 * hl;
                        if (keyg > qg) s[r] = -1.0e30f;
                    }
                }
                float p[16];
#pragma unroll
                for (int r = 0; r < 16; ++r) { p[r] = fexp2(s[r]); lsum += p[r]; }

#pragma unroll
                for (int kc = 0; kc < 2; ++kc) {
                    unsigned A0 = pk2(p[kc*8+0], p[kc*8+1]);
                    unsigned A1 = pk2(p[kc*8+2], p[kc*8+3]);
                    unsigned A2 = pk2(p[kc*8+4], p[kc*8+5]);
                    unsigned A3 = pk2(p[kc*8+6], p[kc*8+7]);
                    asm volatile("v_permlane32_swap_b32 %0, %1" : "+v"(A0), "+v"(A2));
                    asm volatile("v_permlane32_swap_b32 %0, %1" : "+v"(A1), "+v"(A3));
                    union { unsigned u[4]; bh8 v; } pb;
                    pb.u[0] = A0; pb.u[1] = A1; pb.u[2] = A2; pb.u[3] = A3;
                    bh8 va0 = *(const bh8*)&smem[b][8192 + vread[0][kc]];
                    bh8 va1 = *(const bh8*)&smem[b][8192 + vread[1][kc]];
                    __builtin_amdgcn_s_setprio(1);
                    o0 = __builtin_amdgcn_mfma_f32_32x32x16_bf16(va0, pb.v, o0, 0, 0, 0);
                    o1 = __builtin_amdgcn_mfma_f32_32x32x16_bf16(va1, pb.v, o1, 0, 0, 0);
                    __builtin_amdgcn_s_setprio(0);
                }
            }

            if (have_next) { __syncthreads(); b ^= 1; }
        }

        // ---- epilogue: reduce l across lane-halves; 4-way kb merge ----
        lsum += __shfl_xor(lsum, 32);
        __syncthreads();
        float* scr = (float*)&smem[0][0];   // 6 x 64 x 36 floats
        union { f16v v; f4 q[4]; } uo0, uo1;
        uo0.v = o0; uo1.v = o1;
        if (kb != 0) {
            float* rec = scr + (((kb - 1) * 2 + qb) * 64 + lane) * 36;
#pragma unroll
            for (int j = 0; j < 4; ++j) {
                *(f4*)(rec + j * 4)      = uo0.q[j];
                *(f4*)(rec + 16 + j * 4) = uo1.q[j];
            }
            rec[32] = lsum;
        }
        __syncthreads();
        if (kb == 0) {
#pragma unroll
            for (int jr = 0; jr < 3; ++jr) {
                const float* rec = scr + ((jr * 2 + qb) * 64 + lane) * 36;
#pragma unroll
                for (int j = 0; j < 4; ++j) {
                    f4 a = *(const f4*)(rec + j * 4);
                    f4 c = *(const f4*)(rec + 16 + j * 4);
#pragma unroll
                    for (int e = 0; e < 4; ++e) {
                        uo0.q[j][e] += a[e];
                        uo1.q[j][e] += c[e];
                    }
                }
                lsum += rec[32];
            }
            const float linv = 1.f / lsum;
            const size_t rowbase = (size_t)qg * DMODEL + head * DK;
#pragma unroll
            for (int a = 0; a < 4; ++a) {
                unsigned lo = (unsigned)f2b(uo0.q[a][0] * linv) | ((unsigned)f2b(uo0.q[a][1] * linv) << 16);
                unsigned hi = (unsigned)f2b(uo0.q[a][2] * linv) | ((unsigned)f2b(uo0.q[a][3] * linv) << 16);
                uint2 pkd; pkd.x = lo; pkd.y = hi;
                *(uint2*)&ctx[rowbase + a * 8 + 4 * hl] = pkd;
                lo = (unsigned)f2b(uo1.q[a][0] * linv) | ((unsigned)f2b(uo1.q[a][1] * linv) << 16);
                hi = (unsigned)f2b(uo1.q[a][2] * linv) | ((unsigned)f2b(uo1.q[a][3] * linv) << 16);
                pkd.x = lo; pkd.y = hi;
                *(uint2*)&ctx[rowbase + 32 + a * 8 + 4 * hl] = pkd;
            }
        }
    }
#undef STAGE
}

// ---------------------------------------------------------------------------
extern "C" void kernel_launch(void* const* d_in, const int* in_sizes, int n_in,
                              void* d_out, int out_size, void* d_ws, size_t ws_size,
                              hipStream_t stream)
{
    const float* x  = (const float*)d_in[0];
    const float* wq = (const float*)d_in[1];
    const float* wk = (const float*)d_in[2];
    const float* wv = (const float*)d_in[3];
    const float* wo = (const float*)d_in[4];
    float* out = (float*)d_out;

    char* ws = (char*)d_ws;
    const size_t MB = 1u << 20;
    u16* xb   = (u16*)(ws);              // 8 MB  [4096][1024] bf16
    u16* wqkv = (u16*)(ws + 8  * MB);    // 6 MB  [3072][1024] bf16 (wq|wk|wv)
    u16* wob  = (u16*)(ws + 14 * MB);    // 2 MB  (contiguous after wqkv)
    u16* Qh   = (u16*)(ws + 16 * MB);    // 8 MB  [h][s][64]  (pre-scaled)
    u16* Kh   = (u16*)(ws + 24 * MB);    // 8 MB
    u16* Vtb  = (u16*)(ws + 32 * MB);    // 8 MB  [h][64][s]
    u16* ctxb = (u16*)(ws + 40 * MB);    // 8 MB  [s][1024]

    const int NCVT = SEQ * DMODEL / 8 + 4 * (DMODEL * DMODEL / 8);   // 1048576
    cvt_all_kernel<<<NCVT / 256, 256, 0, stream>>>(x, wq, wk, wv, wo, xb, wqkv);

    dim3 gqkv(3 * DMODEL / 128, SEQ / 128);   // (24, 32) = 768 blocks
    gemm_bt<2><<<gqkv, 256, 0, stream>>>(xb, wqkv, nullptr, Qh, Kh, Vtb,
                                         SEQ, 3 * DMODEL, DMODEL);

    attn_mfma_kernel<<<dim3(512), 512, 0, stream>>>(Qh, Kh, Vtb, ctxb);

    dim3 go(DMODEL / 64, SEQ / 128);          // (16, 32) = 512 blocks
    gemm_bt<0><<<go, 256, 0, stream>>>(ctxb, wob, out, nullptr, nullptr, nullptr,
                                       SEQ, DMODEL, DMODEL);
}